// Round 1
// baseline (1776.219 us; speedup 1.0000x reference)
//
#include <hip/hip_runtime.h>

#define NQ   32768
#define NE   8192
#define DIM  256
#define HWsz 1024
#define QB   64
#define CB   256
#define KC   32
#define CBP  260   // padded LDS row stride for e-tile (4-way max on staging writes)

// ---------- se[c] = sum(emb[c,:]^2) ----------
__global__ __launch_bounds__(256) void k_se(const float* __restrict__ emb,
                                            float* __restrict__ se) {
  int w = threadIdx.x >> 6;
  int l = threadIdx.x & 63;
  int r = blockIdx.x * 4 + w;
  float4 v = *(const float4*)(emb + (size_t)r * DIM + l * 4);
  float s = (v.x * v.x + v.y * v.y) + (v.z * v.z + v.w * v.w);
  #pragma unroll
  for (int m = 32; m >= 1; m >>= 1) s += __shfl_xor(s, m);
  if (l == 0) se[r] = s;
}

// ---------- s2[n] = sum over channels of z^2 (z is [B,C,H,W], n=(b,h,w)) ----------
__global__ __launch_bounds__(256) void k_s2(const float* __restrict__ z,
                                            float* __restrict__ s2) {
  __shared__ float red[4][64];
  int blk = blockIdx.x;            // 512 blocks, 64 queries each
  int b = blk >> 4;
  int hw0 = (blk & 15) << 6;
  int q = threadIdx.x & 63;
  int p = threadIdx.x >> 6;
  const float* zp = z + (size_t)(b * DIM + p * 64) * HWsz + hw0 + q;
  float s = 0.f;
  #pragma unroll 4
  for (int c = 0; c < 64; ++c) {
    float v = zp[(size_t)c * HWsz];
    s = fmaf(v, v, s);
  }
  red[p][q] = s;
  __syncthreads();
  if (threadIdx.x < 64) {
    s2[blk * QB + q] = (red[0][q] + red[1][q]) + (red[2][q] + red[3][q]);
  }
}

// ---------- main: fused distance + argmin ----------
// block: 64 queries x all 8192 codes (code tiles of 256, k chunks of 32)
// thread micro-tile: 8 queries x 8 codes (outer product form, k-major LDS)
__global__ __launch_bounds__(256) void k_dist(const float* __restrict__ z,
                                              const float* __restrict__ emb,
                                              const float* __restrict__ se,
                                              const float* __restrict__ s2,
                                              int* __restrict__ best) {
  __shared__ float zt[KC][QB];     // 8 KB
  __shared__ float et[KC][CBP];    // 32.5 KB
  const int tid = threadIdx.x;
  const int blk = blockIdx.x;      // 512
  const int b   = blk >> 4;
  const int hw0 = (blk & 15) << 6;
  const int tq  = tid >> 5;        // 0..7  (query group)
  const int tc  = tid & 31;        // 0..31 (code group)

  float s2q[8];
  #pragma unroll
  for (int i = 0; i < 8; ++i) s2q[i] = s2[blk * QB + tq * 8 + i];

  float bd[8]; int bi[8];
  #pragma unroll
  for (int i = 0; i < 8; ++i) { bd[i] = 3.4028235e38f; bi[i] = 0; }

  for (int ct = 0; ct < NE / CB; ++ct) {
    const int c0 = ct * CB;
    float4 sea = *(const float4*)(se + c0 + tc * 8);
    float4 seb = *(const float4*)(se + c0 + tc * 8 + 4);
    float sev[8] = {sea.x, sea.y, sea.z, sea.w, seb.x, seb.y, seb.z, seb.w};

    float acc[8][8];
    #pragma unroll
    for (int qi = 0; qi < 8; ++qi)
      #pragma unroll
      for (int ci = 0; ci < 8; ++ci) acc[qi][ci] = 0.f;

    for (int kc = 0; kc < DIM / KC; ++kc) {
      const int k0 = kc * KC;
      __syncthreads();
      // stage e tile: read emb rows (8 codes x 128B chunks per instr), transpose into LDS
      float4 ev4[8];
      #pragma unroll
      for (int j = 0; j < 8; ++j)
        ev4[j] = *(const float4*)(emb + (size_t)(c0 + j * 32 + (tid >> 3)) * DIM
                                  + k0 + (tid & 7) * 4);
      // stage z tile: contiguous along query for fixed channel -> k-major directly
      float4 zs[2];
      #pragma unroll
      for (int j = 0; j < 2; ++j) {
        int idx = j * 256 + tid;
        zs[j] = *(const float4*)(z + (size_t)(b * DIM + k0 + (idx >> 4)) * HWsz
                                 + hw0 + (idx & 15) * 4);
      }
      {
        int kb = (tid & 7) * 4;
        int cc = tid >> 3;
        #pragma unroll
        for (int j = 0; j < 8; ++j) {
          et[kb + 0][j * 32 + cc] = ev4[j].x;
          et[kb + 1][j * 32 + cc] = ev4[j].y;
          et[kb + 2][j * 32 + cc] = ev4[j].z;
          et[kb + 3][j * 32 + cc] = ev4[j].w;
        }
      }
      #pragma unroll
      for (int j = 0; j < 2; ++j) {
        int idx = j * 256 + tid;
        *(float4*)&zt[idx >> 4][(idx & 15) * 4] = zs[j];
      }
      __syncthreads();
      #pragma unroll 4
      for (int k = 0; k < KC; ++k) {
        float4 za = *(const float4*)&zt[k][tq * 8];
        float4 zb = *(const float4*)&zt[k][tq * 8 + 4];
        float4 ea = *(const float4*)&et[k][tc * 8];
        float4 eb = *(const float4*)&et[k][tc * 8 + 4];
        float zv[8] = {za.x, za.y, za.z, za.w, zb.x, zb.y, zb.z, zb.w};
        float ev[8] = {ea.x, ea.y, ea.z, ea.w, eb.x, eb.y, eb.z, eb.w};
        #pragma unroll
        for (int qi = 0; qi < 8; ++qi)
          #pragma unroll
          for (int ci = 0; ci < 8; ++ci)
            acc[qi][ci] = fmaf(zv[qi], ev[ci], acc[qi][ci]);
      }
    }
    // epilogue: replicate np rounding d = fl(fl(s2+se) - 2*dot); codes ascending
    #pragma unroll
    for (int qi = 0; qi < 8; ++qi) {
      #pragma unroll
      for (int ci = 0; ci < 8; ++ci) {
        float t = s2q[qi] + sev[ci];
        float d = t - 2.0f * acc[qi][ci];
        if (d < bd[qi]) { bd[qi] = d; bi[qi] = c0 + tc * 8 + ci; }
      }
    }
  }
  // reduce across the 32 code-group lanes (within each 32-lane half-wave)
  #pragma unroll
  for (int qi = 0; qi < 8; ++qi) {
    float d = bd[qi]; int idx = bi[qi];
    #pragma unroll
    for (int m = 16; m >= 1; m >>= 1) {
      float d2 = __shfl_xor(d, m);
      int i2 = __shfl_xor(idx, m);
      if (d2 < d || (d2 == d && i2 < idx)) { d = d2; idx = i2; }
    }
    if (tc == 0) best[blk * QB + tq * 8 + qi] = idx;
  }
}

// ---------- output writer: z_q (straight-through) + indices as float ----------
__global__ __launch_bounds__(256) void k_out(const float* __restrict__ z,
                                             const float* __restrict__ emb,
                                             const int* __restrict__ best,
                                             float* __restrict__ out) {
  int i = blockIdx.x * 256 + threadIdx.x;
  if (i < NQ * DIM) {
    int bb = i >> 18;
    int c  = (i >> 10) & 255;
    int hw = i & 1023;
    int n  = (bb << 10) + hw;
    float zv = z[i];
    float evv = emb[(size_t)best[n] * DIM + c];
    out[i] = zv + (evv - zv);   // replicate z + (z_q - z) elementwise in fp32
  } else {
    int n = i - NQ * DIM;
    out[i] = (float)best[n];
  }
}

extern "C" void kernel_launch(void* const* d_in, const int* in_sizes, int n_in,
                              void* d_out, int out_size, void* d_ws, size_t ws_size,
                              hipStream_t stream) {
  const float* z   = (const float*)d_in[0];
  const float* emb = (const float*)d_in[1];
  float* out = (float*)d_out;

  float* se   = (float*)d_ws;          // 8192
  float* s2   = se + NE;               // 32768
  int*   best = (int*)(s2 + NQ);       // 32768  (total ws use ~288 KB)

  k_se  <<<NE / 4, 256, 0, stream>>>(emb, se);
  k_s2  <<<NQ / QB, 256, 0, stream>>>(z, s2);
  k_dist<<<NQ / QB, 256, 0, stream>>>(z, emb, se, s2, best);
  k_out <<<(NQ * DIM + NQ) / 256, 256, 0, stream>>>(z, emb, best, out);
}

// Round 2
// 442.714 us; speedup vs baseline: 4.0121x; 4.0121x over previous
//
#include <hip/hip_runtime.h>

#define NQ   32768
#define NE   8192
#define DIM  256
#define HWsz 1024
#define MARGIN 5e-4f

typedef __attribute__((ext_vector_type(8))) short short8;
typedef __attribute__((ext_vector_type(4))) float f32x4;

#define GLDS16(gp, lp) __builtin_amdgcn_global_load_lds( \
    (const __attribute__((address_space(1))) unsigned int*)(gp), \
    (__attribute__((address_space(3))) unsigned int*)(lp), 16, 0, 0)

static __device__ inline unsigned short f2bf(float f) {
  unsigned int u = __float_as_uint(f);
  unsigned int r = (u + 0x7fff + ((u >> 16) & 1)) >> 16;
  return (unsigned short)r;
}

// ---------- se[c] = sum(emb[c,:]^2) ----------
__global__ __launch_bounds__(256) void k_se(const float* __restrict__ emb,
                                            float* __restrict__ se) {
  int w = threadIdx.x >> 6;
  int l = threadIdx.x & 63;
  int r = blockIdx.x * 4 + w;
  float4 v = *(const float4*)(emb + (size_t)r * DIM + l * 4);
  float s = (v.x * v.x + v.y * v.y) + (v.z * v.z + v.w * v.w);
  #pragma unroll
  for (int m = 32; m >= 1; m >>= 1) s += __shfl_xor(s, m);
  if (l == 0) se[r] = s;
}

// ---------- s2[n] = sum over channels of z^2 (identical to round-1 pass) ----------
__global__ __launch_bounds__(256) void k_s2(const float* __restrict__ z,
                                            float* __restrict__ s2) {
  __shared__ float red[4][64];
  int blk = blockIdx.x;
  int b = blk >> 4;
  int hw0 = (blk & 15) << 6;
  int q = threadIdx.x & 63;
  int p = threadIdx.x >> 6;
  const float* zp = z + (size_t)(b * DIM + p * 64) * HWsz + hw0 + q;
  float s = 0.f;
  #pragma unroll 4
  for (int c = 0; c < 64; ++c) {
    float v = zp[(size_t)c * HWsz];
    s = fmaf(v, v, s);
  }
  red[p][q] = s;
  __syncthreads();
  if (threadIdx.x < 64) {
    s2[blk * 64 + q] = (red[0][q] + red[1][q]) + (red[2][q] + red[3][q]);
  }
}

// ---------- emb fp32 [c][k] -> bf16 fragment-major ebf ----------
// chunk gid: t=gid>>9, kk=(gid>>6)&7, l=gid&63 -> 8 bf16 from
// emb[t*16+(l&15)][(l>>4)*8+32*kk + j], stored linearly at gid*8 elements.
__global__ __launch_bounds__(256) void k_ebf(const float* __restrict__ emb,
                                             unsigned short* __restrict__ ebf) {
  int gid = blockIdx.x * 256 + threadIdx.x;
  int t = gid >> 9;
  int kk = (gid >> 6) & 7;
  int l = gid & 63;
  int row = t * 16 + (l & 15);
  int col = (l >> 4) * 8 + kk * 32;
  const float* src = emb + (size_t)row * DIM + col;
  float4 v0 = *(const float4*)(src);
  float4 v1 = *(const float4*)(src + 4);
  unsigned short o[8] = {f2bf(v0.x), f2bf(v0.y), f2bf(v0.z), f2bf(v0.w),
                         f2bf(v1.x), f2bf(v1.y), f2bf(v1.z), f2bf(v1.w)};
  *(short8*)(ebf + (size_t)gid * 8) = *(short8*)o;
}

// ---------- z [b][ch][hw] fp32 -> za [q][ch] bf16 (tiled LDS transpose) ----------
__global__ __launch_bounds__(256) void k_tr(const float* __restrict__ z,
                                            unsigned short* __restrict__ za) {
  __shared__ float lt[64][65];
  int blk = blockIdx.x;
  int b = blk >> 6;
  int r = blk & 63;
  int ch0 = (r >> 4) * 64;
  int hw0 = (r & 15) * 64;
  int tid = threadIdx.x;
  #pragma unroll
  for (int p = 0; p < 4; ++p) {
    int idx = p * 256 + tid;
    int ch = idx >> 4;
    int hc = idx & 15;
    float4 v = *(const float4*)(z + (size_t)(b * DIM + ch0 + ch) * HWsz + hw0 + hc * 4);
    lt[ch][hc * 4 + 0] = v.x;
    lt[ch][hc * 4 + 1] = v.y;
    lt[ch][hc * 4 + 2] = v.z;
    lt[ch][hc * 4 + 3] = v.w;
  }
  __syncthreads();
  #pragma unroll
  for (int p = 0; p < 2; ++p) {
    int idx = p * 256 + tid;
    int hw = idx >> 3;
    int cc = idx & 7;
    unsigned short o[8];
    #pragma unroll
    for (int j = 0; j < 8; ++j) o[j] = f2bf(lt[cc * 8 + j][hw]);
    *(short8*)(za + (size_t)((b << 10) + hw0 + hw) * DIM + ch0 + cc * 8) = *(short8*)o;
  }
}

// ---------- pass A: approx scores via MFMA, per-query max ----------
// grid 512: qb = blk>>2 (256 queries), ct = blk&3 (2048 codes)
__global__ __launch_bounds__(256, 2) void k_score1(const unsigned short* __restrict__ za,
                                                   const unsigned short* __restrict__ ebf,
                                                   float* __restrict__ qbest) {
  __shared__ __align__(16) char ebt[2][8192];
  const int tid = threadIdx.x, lane = tid & 63, w = tid >> 6;
  const int blk = blockIdx.x, qb = blk >> 2, ct = blk & 3;
  const int q0 = qb * 256 + w * 64;

  short8 a[4][8];
  #pragma unroll
  for (int f = 0; f < 4; ++f)
    #pragma unroll
    for (int kk = 0; kk < 8; ++kk)
      a[f][kk] = *(const short8*)(za + (size_t)(q0 + f * 16 + (lane & 15)) * DIM
                                  + (lane >> 4) * 8 + kk * 32);

  float bv[4][4];
  #pragma unroll
  for (int f = 0; f < 4; ++f)
    #pragma unroll
    for (int r = 0; r < 4; ++r) bv[f][r] = -3.4028235e38f;

  const char* ebase = (const char*)ebf + (size_t)ct * 128 * 8192;
  GLDS16(ebase + tid * 16, &ebt[0][w * 1024]);
  GLDS16(ebase + 4096 + tid * 16, &ebt[0][w * 1024 + 4096]);
  __syncthreads();

  int cur = 0;
  for (int t = 0; t < 128; ++t) {
    if (t + 1 < 128) {
      const char* src = ebase + (size_t)(t + 1) * 8192;
      GLDS16(src + tid * 16, &ebt[cur ^ 1][w * 1024]);
      GLDS16(src + 4096 + tid * 16, &ebt[cur ^ 1][w * 1024 + 4096]);
    }
    f32x4 acc[4];
    #pragma unroll
    for (int f = 0; f < 4; ++f) acc[f] = (f32x4){0.f, 0.f, 0.f, 0.f};
    #pragma unroll
    for (int kk = 0; kk < 8; ++kk) {
      short8 bfrag = *(const short8*)&ebt[cur][kk * 1024 + lane * 16];
      #pragma unroll
      for (int f = 0; f < 4; ++f)
        acc[f] = __builtin_amdgcn_mfma_f32_16x16x32_bf16(a[f][kk], bfrag, acc[f], 0, 0, 0);
    }
    #pragma unroll
    for (int f = 0; f < 4; ++f)
      #pragma unroll
      for (int r = 0; r < 4; ++r) bv[f][r] = fmaxf(bv[f][r], acc[f][r]);
    __syncthreads();
    cur ^= 1;
  }
  // reduce across the 16 lanes (l&15) holding each query-row
  #pragma unroll
  for (int f = 0; f < 4; ++f)
    #pragma unroll
    for (int r = 0; r < 4; ++r) {
      float v = bv[f][r];
      #pragma unroll
      for (int m = 1; m <= 8; m <<= 1) v = fmaxf(v, __shfl_xor(v, m));
      if ((lane & 15) == 0)
        qbest[(size_t)ct * NQ + q0 + f * 16 + (lane >> 4) * 4 + r] = v;
    }
}

// ---------- merge: qthr = max over ctiles - margin; reset cnt ----------
__global__ __launch_bounds__(256) void k_merge(const float* __restrict__ qbest,
                                               float* __restrict__ qthr,
                                               int* __restrict__ cnt) {
  int q = blockIdx.x * 256 + threadIdx.x;
  float m = qbest[q];
  #pragma unroll
  for (int ct = 1; ct < 4; ++ct) m = fmaxf(m, qbest[(size_t)ct * NQ + q]);
  qthr[q] = m - MARGIN;
  cnt[q] = 0;
}

// ---------- pass B: recompute scores, collect candidates above threshold ----------
__global__ __launch_bounds__(256, 2) void k_score2(const unsigned short* __restrict__ za,
                                                   const unsigned short* __restrict__ ebf,
                                                   const float* __restrict__ qthr,
                                                   int* __restrict__ cnt,
                                                   int* __restrict__ cand) {
  __shared__ __align__(16) char ebt[2][8192];
  const int tid = threadIdx.x, lane = tid & 63, w = tid >> 6;
  const int blk = blockIdx.x, qb = blk >> 2, ct = blk & 3;
  const int q0 = qb * 256 + w * 64;

  short8 a[4][8];
  #pragma unroll
  for (int f = 0; f < 4; ++f)
    #pragma unroll
    for (int kk = 0; kk < 8; ++kk)
      a[f][kk] = *(const short8*)(za + (size_t)(q0 + f * 16 + (lane & 15)) * DIM
                                  + (lane >> 4) * 8 + kk * 32);

  float thr[4][4];
  #pragma unroll
  for (int f = 0; f < 4; ++f)
    #pragma unroll
    for (int r = 0; r < 4; ++r)
      thr[f][r] = qthr[q0 + f * 16 + (lane >> 4) * 4 + r];

  const char* ebase = (const char*)ebf + (size_t)ct * 128 * 8192;
  GLDS16(ebase + tid * 16, &ebt[0][w * 1024]);
  GLDS16(ebase + 4096 + tid * 16, &ebt[0][w * 1024 + 4096]);
  __syncthreads();

  int cur = 0;
  for (int t = 0; t < 128; ++t) {
    if (t + 1 < 128) {
      const char* src = ebase + (size_t)(t + 1) * 8192;
      GLDS16(src + tid * 16, &ebt[cur ^ 1][w * 1024]);
      GLDS16(src + 4096 + tid * 16, &ebt[cur ^ 1][w * 1024 + 4096]);
    }
    f32x4 acc[4];
    #pragma unroll
    for (int f = 0; f < 4; ++f) acc[f] = (f32x4){0.f, 0.f, 0.f, 0.f};
    #pragma unroll
    for (int kk = 0; kk < 8; ++kk) {
      short8 bfrag = *(const short8*)&ebt[cur][kk * 1024 + lane * 16];
      #pragma unroll
      for (int f = 0; f < 4; ++f)
        acc[f] = __builtin_amdgcn_mfma_f32_16x16x32_bf16(a[f][kk], bfrag, acc[f], 0, 0, 0);
    }
    int c = ct * 2048 + t * 16 + (lane & 15);
    #pragma unroll
    for (int f = 0; f < 4; ++f)
      #pragma unroll
      for (int r = 0; r < 4; ++r) {
        if (acc[f][r] > thr[f][r]) {
          int q = q0 + f * 16 + (lane >> 4) * 4 + r;
          int pos = atomicAdd(&cnt[q], 1);
          if (pos < 64) cand[((size_t)q << 6) + pos] = c;
        }
      }
    __syncthreads();
    cur ^= 1;
  }
}

// ---------- exact fp32 rescore of candidates (wave per query) ----------
__global__ __launch_bounds__(256) void k_rescore(const float* __restrict__ z,
                                                 const float* __restrict__ emb,
                                                 const float* __restrict__ se,
                                                 const float* __restrict__ s2,
                                                 const int* __restrict__ cnt,
                                                 const int* __restrict__ cand,
                                                 int* __restrict__ best) {
  int q = blockIdx.x * 4 + (threadIdx.x >> 6);
  int lane = threadIdx.x & 63;
  int b = q >> 10;
  int hw = q & 1023;
  float zr[4];
  #pragma unroll
  for (int j = 0; j < 4; ++j)
    zr[j] = z[(size_t)((b << 8) + lane * 4 + j) * HWsz + hw];
  float s2q = s2[q];
  int n = cnt[q];
  bool full = (n <= 0) || (n > 64);
  int count = full ? NE : n;
  float bd = 3.4028235e38f;
  int bi = 0x7fffffff;
  for (int i = 0; i < count; ++i) {
    int c = full ? i : cand[((size_t)q << 6) + i];
    float4 e = *(const float4*)(emb + (size_t)c * DIM + lane * 4);
    float p = fmaf(zr[0], e.x, fmaf(zr[1], e.y, fmaf(zr[2], e.z, zr[3] * e.w)));
    #pragma unroll
    for (int m = 1; m <= 32; m <<= 1) p += __shfl_xor(p, m);
    float t = s2q + se[c];
    float d = t - 2.0f * p;
    if (d < bd || (d == bd && c < bi)) { bd = d; bi = c; }
  }
  if (lane == 0) best[q] = bi;
}

// ---------- output writer: z_q (straight-through) + indices as float ----------
__global__ __launch_bounds__(256) void k_out(const float* __restrict__ z,
                                             const float* __restrict__ emb,
                                             const int* __restrict__ best,
                                             float* __restrict__ out) {
  int i = blockIdx.x * 256 + threadIdx.x;
  if (i < NQ * DIM) {
    int bb = i >> 18;
    int c  = (i >> 10) & 255;
    int hw = i & 1023;
    int n  = (bb << 10) + hw;
    float zv = z[i];
    float evv = emb[(size_t)best[n] * DIM + c];
    out[i] = zv + (evv - zv);
  } else {
    int n = i - NQ * DIM;
    out[i] = (float)best[n];
  }
}

extern "C" void kernel_launch(void* const* d_in, const int* in_sizes, int n_in,
                              void* d_out, int out_size, void* d_ws, size_t ws_size,
                              hipStream_t stream) {
  const float* z   = (const float*)d_in[0];
  const float* emb = (const float*)d_in[1];
  float* out = (float*)d_out;

  char* ws = (char*)d_ws;
  float* se    = (float*)(ws + 0);                 //  32 KB
  float* s2    = (float*)(ws + 32768);             // 128 KB
  float* qbest = (float*)(ws + 163840);            // 512 KB
  float* qthr  = (float*)(ws + 688128);            // 128 KB
  int*   cnt   = (int*)  (ws + 819200);            // 128 KB
  int*   best  = (int*)  (ws + 950272);            // 128 KB
  int*   cand  = (int*)  (ws + 1081344);           //   8 MB
  unsigned short* za  = (unsigned short*)(ws + 9469952);   // 16 MB
  unsigned short* ebf = (unsigned short*)(ws + 26247168);  //  4 MB

  k_se     <<<NE / 4, 256, 0, stream>>>(emb, se);
  k_s2     <<<NQ / 64, 256, 0, stream>>>(z, s2);
  k_ebf    <<<1024, 256, 0, stream>>>(emb, ebf);
  k_tr     <<<2048, 256, 0, stream>>>(z, za);
  k_score1 <<<512, 256, 0, stream>>>(za, ebf, qbest);
  k_merge  <<<NQ / 256, 256, 0, stream>>>(qbest, qthr, cnt);
  k_score2 <<<512, 256, 0, stream>>>(za, ebf, qthr, cnt, cand);
  k_rescore<<<NQ / 4, 256, 0, stream>>>(z, emb, se, s2, cnt, cand, best);
  k_out    <<<(NQ * DIM + NQ) / 256, 256, 0, stream>>>(z, emb, best, out);
}